// Round 9
// baseline (655.350 us; speedup 1.0000x reference)
//
#include <hip/hip_runtime.h>

#define POOL_SHIFT 2
#define GRID_DIM 64
#define NUM_CELLS 4096
#define NCH 64
#define BATCH 64
#define QCS 16                      // 16 channel-quads of 4 channels
#define SENTINEL ((int)0x80000000)  // maps to no real float (only NaN)
#define POOL_REPS 3                 // MEASUREMENT ROUND: 3x idempotent pool

typedef float vf4 __attribute__((ext_vector_type(4)));

// ---- K0: batch row ranges (batch is sorted) ----
__global__ __launch_bounds__(256) void bounds_kernel(
    const int* __restrict__ batch, int* __restrict__ bstart, int n) {
    int p = blockIdx.x * blockDim.x + threadIdx.x;
    if (p >= n) return;
    int b = batch[p];
    if (p == 0) {
        for (int i = 0; i <= b; ++i) bstart[i] = 0;
    } else {
        int pb = batch[p - 1];
        for (int i = pb + 1; i <= b; ++i) bstart[i] = p;
    }
    if (p == n - 1) {
        for (int i = b + 1; i <= BATCH; ++i) bstart[i] = n;
    }
}

// order-preserving float->int map (finite floats; inputs have no NaN)
__device__ __forceinline__ int fmap(float f) {
    int i = __float_as_int(f);
    return i >= 0 ? i : (i ^ 0x7fffffff);
}
__device__ __forceinline__ float funmap(int m) {
    if (m == SENTINEL) return 0.0f;              // empty cell -> 0 (ref semantics)
    return __int_as_float(m >= 0 ? m : (m ^ 0x7fffffff));
}

__device__ __forceinline__ void accum(int* acc, int2 pp, vf4 v) {
    int c = ((pp.x >> POOL_SHIFT) << 6) | (pp.y >> POOL_SHIFT);
    // plane-major acc[j][c]: bank = c & 31 (4096 % 32 == 0) -> ~2-way, free
    atomicMax(&acc[0 * NUM_CELLS + c], fmap(v.x));
    atomicMax(&acc[1 * NUM_CELLS + c], fmap(v.y));
    atomicMax(&acc[2 * NUM_CELLS + c], fmap(v.z));
    atomicMax(&acc[3 * NUM_CELLS + c], fmap(v.w));
}

// ---- K1: persistent (batch-pair, channel-quad) workgroups ----
// MEASUREMENT: whole body (init+accumulate+flush) repeated POOL_REPS
// times, idempotent. Opaque-pointer asm per rep prevents the compiler
// from proving reps redundant. Purpose: push pool above the profiler's
// top-5 cutoff to read FETCH_SIZE (sector-dedup factor on the stride-256
// x reads), SQ_LDS_BANK_CONFLICT (atomic serialization), VALUBusy.
__global__ __launch_bounds__(256, 2) void pool_kernel(
    const float* __restrict__ x, const int* __restrict__ pos,
    const int* __restrict__ bstart, float* __restrict__ out) {
    __shared__ int acc[4 * NUM_CELLS];   // 64 KB, plane-major [j][cell]
    const int L   = (int)blockIdx.x;
    const int xcd = L & 7;
    const int qc  = (L >> 3) & 15;
    const int grp = L >> 7;              // 0..3
    const int b0  = grp * 8 + xcd;       // 0..31
    const int t   = threadIdx.x;

    for (int rep = 0; rep < POOL_REPS; ++rep) {
        // opaque copies: compiler cannot prove reps redundant
        const float* xp = x;
        const int* pp_ = pos;
        const int* bsp = bstart;
        float* op = out;
        asm volatile("" : "+v"(xp), "+v"(pp_), "+v"(bsp), "+v"(op));

        const vf4* xq  = (const vf4*)xp;   // row r, quad qc -> xq[r*16 + qc]
        const int2* pq = (const int2*)pp_;

        for (int half = 0; half < 2; ++half) {
            const int b = b0 + 32 * half;

            for (int i = t; i < 4 * NUM_CELLS; i += 256) acc[i] = SENTINEL;
            __syncthreads();

            const int r0 = bsp[b], r1 = bsp[b + 1];

            int r = r0 + t;
            // 4 independent row-loads in flight per lane
            for (; r + 768 < r1; r += 1024) {
                int2 pp0 = pq[r];
                int2 pp1 = pq[r + 256];
                int2 pp2 = pq[r + 512];
                int2 pp3 = pq[r + 768];
                vf4 v0 = xq[(size_t)r * QCS + qc];
                vf4 v1 = xq[(size_t)(r + 256) * QCS + qc];
                vf4 v2 = xq[(size_t)(r + 512) * QCS + qc];
                vf4 v3 = xq[(size_t)(r + 768) * QCS + qc];
                accum(acc, pp0, v0);
                accum(acc, pp1, v1);
                accum(acc, pp2, v2);
                accum(acc, pp3, v3);
            }
            for (; r < r1; r += 256) {
                int2 pp = pq[r];
                vf4 v = xq[(size_t)r * QCS + qc];
                accum(acc, pp, v);
            }
            __syncthreads();

            // flush: channels qc*4 .. qc*4+3 of every cell of batch b
            const size_t obase = (size_t)b * NUM_CELLS * NCH + (size_t)qc * 4;
            for (int c = t; c < NUM_CELLS; c += 256) {
                vf4 o;
                o.x = funmap(acc[0 * NUM_CELLS + c]);
                o.y = funmap(acc[1 * NUM_CELLS + c]);
                o.z = funmap(acc[2 * NUM_CELLS + c]);
                o.w = funmap(acc[3 * NUM_CELLS + c]);
                *(vf4*)&op[obase + (size_t)c * NCH] = o;
            }
            __syncthreads();   // flush reads acc before next half re-inits
        }
    }
}

extern "C" void kernel_launch(void* const* d_in, const int* in_sizes, int n_in,
                              void* d_out, int out_size, void* d_ws, size_t ws_size,
                              hipStream_t stream) {
    const float* x   = (const float*)d_in[0];
    const int* pos   = (const int*)d_in[1];
    const int* batch = (const int*)d_in[2];
    float* out = (float*)d_out;
    int n = in_sizes[2];

    int* bstart = (int*)d_ws;           // BATCH + 1 ints

    bounds_kernel<<<(n + 255) / 256, 256, 0, stream>>>(batch, bstart, n);
    pool_kernel<<<512, 256, 0, stream>>>(x, pos, bstart, out);
}

// Round 10
// 416.124 us; speedup vs baseline: 1.5749x; 1.5749x over previous
//
#include <hip/hip_runtime.h>

#define POOL_SHIFT 2
#define GRID_DIM 64
#define NUM_CELLS 4096
#define NCH 64
#define BATCH 64
#define QCS 16                      // 16 channel-quads of 4 channels
#define SENTINEL ((int)0x80000000)  // maps to no real float (only NaN)

typedef float vf4 __attribute__((ext_vector_type(4)));

// ---- K0: batch row ranges (batch is sorted) ----
__global__ __launch_bounds__(256) void bounds_kernel(
    const int* __restrict__ batch, int* __restrict__ bstart, int n) {
    int p = blockIdx.x * blockDim.x + threadIdx.x;
    if (p >= n) return;
    int b = batch[p];
    if (p == 0) {
        for (int i = 0; i <= b; ++i) bstart[i] = 0;
    } else {
        int pb = batch[p - 1];
        for (int i = pb + 1; i <= b; ++i) bstart[i] = p;
    }
    if (p == n - 1) {
        for (int i = b + 1; i <= BATCH; ++i) bstart[i] = n;
    }
}

// order-preserving float->int map (finite floats; inputs have no NaN)
__device__ __forceinline__ int fmap(float f) {
    int i = __float_as_int(f);
    return i >= 0 ? i : (i ^ 0x7fffffff);
}
__device__ __forceinline__ float funmap(int m) {
    if (m == SENTINEL) return 0.0f;              // empty cell -> 0 (ref semantics)
    return __int_as_float(m >= 0 ? m : (m ^ 0x7fffffff));
}

// plane j of cell c at acc[(j<<12) + (c ^ (j<<3))]: for one lane's 4
// sequential atomics the bank (idx & 31) differs per plane (XOR 0/8/16/24),
// removing the 4x same-bank serialization of the plane-major layout
// (4096 % 32 == 0 put all 4 planes of a cell in one bank).
__device__ __forceinline__ void accum(int* acc, int2 pp, vf4 v) {
    int c = ((pp.x >> POOL_SHIFT) << 6) | (pp.y >> POOL_SHIFT);
    atomicMax(&acc[c ^ 0],                 fmap(v.x));
    atomicMax(&acc[4096 + (c ^ 8)],        fmap(v.y));
    atomicMax(&acc[8192 + (c ^ 16)],       fmap(v.z));
    atomicMax(&acc[12288 + (c ^ 24)],      fmap(v.w));
}

// ---- K1: persistent (batch-pair, channel-quad) workgroups ----
// Round-9 measurement: pool is LATENCY-bound (occupancy 20%, VALU 9.5%,
// HBM 28%, conflicts minor). Fix: 512-thread WGs at the same 64 KB LDS
// -> 2 blocks/CU = 16 waves/CU (was 8), plus 6-deep row MLP per lane.
// Grid stays 512 persistent WGs (one co-resident round; sibling qc WGs
// of a batch share an XCD so L2 merges the 16-B/256-B strided x reads —
// validated by round-9 FETCH ≈ 177 MB/rep).
__global__ __launch_bounds__(512, 4) void pool_kernel(
    const float* __restrict__ x, const int* __restrict__ pos,
    const int* __restrict__ bstart, float* __restrict__ out) {
    __shared__ int acc[4 * NUM_CELLS];   // 64 KB, swizzled plane-major
    const int L   = (int)blockIdx.x;
    const int xcd = L & 7;
    const int qc  = (L >> 3) & 15;
    const int grp = L >> 7;              // 0..3
    const int b0  = grp * 8 + xcd;       // 0..31
    const int t   = threadIdx.x;         // 0..511

    const vf4* xq  = (const vf4*)x;      // row r, quad qc -> xq[r*16 + qc]
    const int2* pq = (const int2*)pos;

    for (int half = 0; half < 2; ++half) {
        const int b = b0 + 32 * half;

        for (int i = t; i < 4 * NUM_CELLS; i += 512) acc[i] = SENTINEL;
        __syncthreads();

        const int r0 = bstart[b], r1 = bstart[b + 1];

        int r = r0 + t;
        // 6 independent row-loads in flight per lane
        for (; r + 2560 < r1; r += 3072) {
            int2 pp0 = pq[r];
            int2 pp1 = pq[r + 512];
            int2 pp2 = pq[r + 1024];
            int2 pp3 = pq[r + 1536];
            int2 pp4 = pq[r + 2048];
            int2 pp5 = pq[r + 2560];
            vf4 v0 = xq[(size_t)r * QCS + qc];
            vf4 v1 = xq[(size_t)(r + 512) * QCS + qc];
            vf4 v2 = xq[(size_t)(r + 1024) * QCS + qc];
            vf4 v3 = xq[(size_t)(r + 1536) * QCS + qc];
            vf4 v4 = xq[(size_t)(r + 2048) * QCS + qc];
            vf4 v5 = xq[(size_t)(r + 2560) * QCS + qc];
            accum(acc, pp0, v0);
            accum(acc, pp1, v1);
            accum(acc, pp2, v2);
            accum(acc, pp3, v3);
            accum(acc, pp4, v4);
            accum(acc, pp5, v5);
        }
        for (; r < r1; r += 512) {
            int2 pp = pq[r];
            vf4 v = xq[(size_t)r * QCS + qc];
            accum(acc, pp, v);
        }
        __syncthreads();

        // flush: channels qc*4 .. qc*4+3 of every cell of batch b
        const size_t obase = (size_t)b * NUM_CELLS * NCH + (size_t)qc * 4;
        for (int c = t; c < NUM_CELLS; c += 512) {
            vf4 o;
            o.x = funmap(acc[c ^ 0]);
            o.y = funmap(acc[4096 + (c ^ 8)]);
            o.z = funmap(acc[8192 + (c ^ 16)]);
            o.w = funmap(acc[12288 + (c ^ 24)]);
            *(vf4*)&out[obase + (size_t)c * NCH] = o;  // L2 merges quad-siblings
        }
        __syncthreads();   // flush reads acc before next half re-inits
    }
}

extern "C" void kernel_launch(void* const* d_in, const int* in_sizes, int n_in,
                              void* d_out, int out_size, void* d_ws, size_t ws_size,
                              hipStream_t stream) {
    const float* x   = (const float*)d_in[0];
    const int* pos   = (const int*)d_in[1];
    const int* batch = (const int*)d_in[2];
    float* out = (float*)d_out;
    int n = in_sizes[2];

    int* bstart = (int*)d_ws;           // BATCH + 1 ints

    bounds_kernel<<<(n + 255) / 256, 256, 0, stream>>>(batch, bstart, n);
    pool_kernel<<<512, 512, 0, stream>>>(x, pos, bstart, out);
}